// Round 9
// baseline (152.736 us; speedup 1.0000x reference)
//
#include <hip/hip_runtime.h>
#include <math.h>

#define BB 8
#define DD 128
#define HWD 65536    // 256*256
#define NBLK 8192    // 524288 px / 64 px per block

__device__ __forceinline__ float warp_red_sum(float v) {
#pragma unroll
    for (int off = 32; off > 0; off >>= 1) v += __shfl_down(v, off, 64);
    return v;
}

// swizzled LDS dword index for channel c, pixel p (16B-granular XOR keeps
// b128 writes aligned; read perm covers 64 distinct dwords -> 2-way free)
__device__ __forceinline__ int st_idx(int c, int p) {
    return (c << 6) + (((p & ~3) ^ ((c & 7) << 2)) | (p & 3));
}

// 512 threads = 8 waves. Block = 64 pixels x 128 channels.
// Stage: pack (s, t-center) as 2xbf16 in one dword -> 32 KB tile -> 4 blocks/CU.
// Pass 1/2 read LDS only: the two-pass working set finally has a home the
// register allocator can't remat or spill.
__global__ __launch_bounds__(512, 2)
void pixel_dino_main(const float* __restrict__ s_feats,
                     const float* __restrict__ t_feats,
                     const float* __restrict__ center,
                     const void*  __restrict__ mask,
                     const float* __restrict__ orig_x,
                     float* __restrict__ ws) {
    const float TAU_S_INV = 10.0f, TAU_T_INV = 25.0f, EPSN = 1e-12f;
    const int tid  = threadIdx.x;
    const int lane = tid & 63;
    const int wave = tid >> 6;                      // 0..7
    const int b    = blockIdx.x >> 10;              // 1024 blocks per image
    const int pix0 = (blockIdx.x & 1023) << 6;
    const size_t base = (size_t)b * (DD * HWD) + pix0;

    __shared__ unsigned int st[DD * 64];            // 32 KB: packed {s_bf16, t_bf16}
    __shared__ float red[3][8][64];                 // 6 KB
    __shared__ float tot[3][64];                    // 0.75 KB

    // --- self-detect mask dtype from first 1024 bytes (ballots, ~free) ---
    // flag: 0=uint8, 1=int32, 2=float32, 3=int64. All-zero window -> 0 (safe).
    const uint4 mw = ((const uint4*)mask)[lane];
    const unsigned int anyw = mw.x | mw.y | mw.z | mw.w;
    const unsigned long long nz  = __ballot(anyw != 0u);
    const unsigned long long gt1 = __ballot((anyw & 0xFEFEFEFEu) != 0u);
    const unsigned long long m4  = __ballot((anyw & 0xFFFFFF00u) != 0u);
    const unsigned long long m84 = __ballot(((mw.y | mw.w) & 0xFFu) != 0u);
    const int flag = gt1 ? 2 : (m4 ? 0 : (m84 ? 1 : (nz ? 3 : 0)));

    // ---- stage: thread (c0 = tid>>4, li = tid&15) loads float4 of 4 px ----
    {
        const int c0 = tid >> 4;
        const int li = tid & 15;                    // float4 index within 64-px row
        const float* sB = s_feats + base + (li << 2);
        const float* tB = t_feats + base + (li << 2);
#pragma unroll 2
        for (int r = 0; r < 4; ++r) {
            const int c = c0 + (r << 5);
            const float4 s4 = *reinterpret_cast<const float4*>(sB + (size_t)c * HWD);
            float4 t4 = *reinterpret_cast<const float4*>(tB + (size_t)c * HWD);
            const float cc = center[c];
            t4.x -= cc; t4.y -= cc; t4.z -= cc; t4.w -= cc;
            uint4 w;
            asm("v_cvt_pk_bf16_f32 %0, %1, %2" : "=v"(w.x) : "v"(s4.x), "v"(t4.x));
            asm("v_cvt_pk_bf16_f32 %0, %1, %2" : "=v"(w.y) : "v"(s4.y), "v"(t4.y));
            asm("v_cvt_pk_bf16_f32 %0, %1, %2" : "=v"(w.z) : "v"(s4.z), "v"(t4.z));
            asm("v_cvt_pk_bf16_f32 %0, %1, %2" : "=v"(w.w) : "v"(s4.w), "v"(t4.w));
            *reinterpret_cast<uint4*>(&st[st_idx(c, li << 2)]) = w;
        }
    }
    __syncthreads();

    // ---- pass 1: norm sums. lane = pixel, wave owns 16 channels ----
    const int d0 = wave << 4;
    float ss = 0.f, tt = 0.f;
#pragma unroll
    for (int k = 0; k < 16; ++k) {
        const unsigned int u = st[st_idx(d0 + k, lane)];
        const float sf = __uint_as_float(u << 16);
        const float tf = __uint_as_float(u & 0xFFFF0000u);
        ss = fmaf(sf, sf, ss);
        tt = fmaf(tf, tf, tt);
    }
    red[0][wave][lane] = ss; red[1][wave][lane] = tt;
    __syncthreads();
    if (tid < 128) {                      // 2 quantities x 64 pixels
        const int q = tid >> 6, p = tid & 63;
        float v = 0.f;
#pragma unroll
        for (int w = 0; w < 8; ++w) v += red[q][w][p];
        tot[q][p] = v;
    }
    __syncthreads();
    const float rs = TAU_S_INV / fmaxf(sqrtf(tot[0][lane]), EPSN);
    const float rt = TAU_T_INV / fmaxf(sqrtf(tot[1][lane]), EPSN);

    // ---- pass 2: exp sums from LDS (no max-sub: |bv|<=10, |av|<=25, fp32-safe) ----
    float eb = 0.f, ea = 0.f, eab = 0.f;
#pragma unroll
    for (int k = 0; k < 16; ++k) {
        const unsigned int u = st[st_idx(d0 + k, lane)];
        const float bv = __uint_as_float(u << 16) * rs;
        const float av = __uint_as_float(u & 0xFFFF0000u) * rt;
        const float e2 = __expf(av);
        eb += __expf(bv);
        ea += e2;
        eab = fmaf(e2, bv, eab);
    }
    __syncthreads();
    red[0][wave][lane] = eb; red[1][wave][lane] = ea; red[2][wave][lane] = eab;
    __syncthreads();
    if (tid < 192) {                      // 3 quantities x 64 pixels
        const int q = tid >> 6, p = tid & 63;
        float v = 0.f;
#pragma unroll
        for (int w = 0; w < 8; ++w) v += red[q][w][p];
        tot[q][p] = v;
    }
    __syncthreads();

    if (wave == 0) {
        const float loss = __logf(tot[0][lane]) - tot[2][lane] / tot[1][lane];

        const int gidx = b * HWD + pix0 + lane;
        bool mval;
        if (flag == 0)      mval = ((const unsigned char*)mask)[gidx] != 0;
        else if (flag == 1) mval = ((const int*)mask)[gidx] != 0;
        else if (flag == 2) mval = ((const float*)mask)[gidx] != 0.f;
        else                mval = ((const long long*)mask)[gidx] != 0;
        const bool valid = (orig_x[gidx] != 0.f) && !mval;

        float l = valid ? loss : 0.f;
        float c = valid ? 1.f  : 0.f;
        l = warp_red_sum(l);
        c = warp_red_sum(c);
        if (lane == 0) {
            atomicAdd(&ws[8 + b], l);
            atomicAdd(&ws[16 + b], c);
        }
    }
}

__global__ void finalize_kernel(const float* __restrict__ ws, float* __restrict__ out) {
    if (threadIdx.x == 0 && blockIdx.x == 0) {
        float acc = 0.f, nnz = 0.f, totc = 0.f;
#pragma unroll
        for (int i = 0; i < BB; ++i) {
            float c = ws[16 + i];
            totc += c;
            if (c > 0.f) { acc += ws[8 + i] / c; nnz += 1.f; }
        }
        out[0] = (totc > 0.f) ? acc / fmaxf(nnz, 1.f) : 0.f;
    }
}

extern "C" void kernel_launch(void* const* d_in, const int* in_sizes, int n_in,
                              void* d_out, int out_size, void* d_ws, size_t ws_size,
                              hipStream_t stream) {
    const float* s_feats = (const float*)d_in[0];
    const float* t_feats = (const float*)d_in[1];
    const float* center  = (const float*)d_in[2];
    const void*  mask    = d_in[3];
    const float* orig_x  = (const float*)d_in[4];
    float* ws = (float*)d_ws;

    hipMemsetAsync(d_ws, 0, 128, stream);
    pixel_dino_main<<<NBLK, 512, 0, stream>>>(s_feats, t_feats, center, mask,
                                              orig_x, ws);
    finalize_kernel<<<1, 64, 0, stream>>>(ws, (float*)d_out);
}